// Round 11
// baseline (73.816 us; speedup 1.0000x reference)
//
#include <hip/hip_runtime.h>

#define D    64
#define NROW 8192

typedef _Float16 f16x8 __attribute__((ext_vector_type(8)));
typedef float    f32x4 __attribute__((ext_vector_type(4)));

// ---------------------------------------------------------------------------
// Pre-pass (R1-proven): row squared-norms into workspace.
// sq[0..8191] = ||x_row||^2, sq[8192..16383] = ||y_row||^2.
// ---------------------------------------------------------------------------
__global__ __launch_bounds__(256) void rbf_rowsq(const float* __restrict__ x,
                                                 const float* __restrict__ y,
                                                 float* __restrict__ sq) {
    int tid = blockIdx.x * blockDim.x + threadIdx.x;  // 0..16383
    const float* src = (tid < NROW) ? x : y;
    int row = tid & (NROW - 1);
    const float4* p = reinterpret_cast<const float4*>(src + row * D);
    float s = 0.f;
#pragma unroll
    for (int i = 0; i < D / 4; ++i) {
        float4 v = p[i];
        s = fmaf(v.x, v.x, s);
        s = fmaf(v.y, v.y, s);
        s = fmaf(v.z, v.z, s);
        s = fmaf(v.w, v.w, s);
    }
    sq[tid] = s;
}

// ---------------------------------------------------------------------------
// Write-locality kernel: 64(x-rows) x 256(y-cols) tile, 512 threads (8 waves).
// Theory: all prior variants write 64-256B segments at 32-KB stride hashed
// across XCDs -> DRAM page thrash caps writes at 4.2 TB/s (fill: 7.0).
// Here each store instr = 1 KB contiguous in ONE row; waves sweep adjacent
// 8-row bands; XCD-chunked block swizzle gives each XCD a contiguous 32-MB
// output slab.
//   - x (64 rows) AND y (256 rows) staged as f16 hi/lo split planes in
//     XOR-swizzled LDS (proven R3/R7 patterns); norms via rbf_rowsq prepass.
//   - MFMA swapped operands (R3-verified): A=y-frag, B=x-frag; per wave
//     2 mt (32 y-cols) x 4 nt (64 x-rows) x 2 kh x 3 products = 48 MFMAs.
//   - epilogue: exp in regs -> transpose via 64-KB LDS stage (overlays Y
//     planes) -> 1-KB-contiguous row stores.
// LDS = 80 KB exactly -> 2 blocks/CU, 16 waves/CU.
// ---------------------------------------------------------------------------
__global__ __launch_bounds__(512, 2) void rbf_strip(const float* __restrict__ x,
                                                    const float* __restrict__ y,
                                                    const float* __restrict__ sq,
                                                    float* __restrict__ out) {
    __shared__ __align__(16) char smem[81920];
    char* const YH = smem;            // f16[256][64] swizzled, 32 KB
    char* const YL = smem + 32768;    // 32 KB
    char* const XH = smem + 65536;    // f16[64][64] swizzled, 8 KB
    char* const XL = smem + 73728;    // 8 KB
    char* const S  = smem;            // f32[64][256] stage, overlays Y planes

    const int t = threadIdx.x;

    // ---- XCD-chunked bijective swizzle (nwg=4096, %8==0) ------------------
    // Each XCD gets 512 consecutive tiles = 16 full row-bands = 32-MB slab.
    const int nb      = (blockIdx.x & 7) * 512 + (blockIdx.x >> 3);
    const int row0    = (nb >> 5) * 64;    // x-row tile (128 bands)
    const int col0    = (nb & 31) * 256;   // y-col tile (32 per band)

    // ---- stage y tile: 256 rows, 2 thr/row (R7-proven coverage) ----------
    {
        const int r    = t & 255;
        const int half = t >> 8;
        const int swz  = (r & 7) << 4;
        const float* yp = y + (size_t)(col0 + r) * D + half * 32;
#pragma unroll
        for (int it = 0; it < 4; ++it) {
            const int c16 = half * 4 + it;          // 16-B chunk 0..7 (full row)
            float4 b0 = *reinterpret_cast<const float4*>(yp + it * 8);
            float4 b1 = *reinterpret_cast<const float4*>(yp + it * 8 + 4);
            float v[8] = {b0.x, b0.y, b0.z, b0.w, b1.x, b1.y, b1.z, b1.w};
            f16x8 h, l;
#pragma unroll
            for (int j = 0; j < 8; ++j) {
                _Float16 hh = (_Float16)v[j];
                h[j] = hh;
                l[j] = (_Float16)(v[j] - (float)hh);
            }
            const int off = r * 128 + ((c16 * 16) ^ swz);
            *reinterpret_cast<f16x8*>(YH + off) = h;
            *reinterpret_cast<f16x8*>(YL + off) = l;
        }
    }
    // ---- stage x tile: 64 rows, 8 thr/row ---------------------------------
    {
        const int r   = t >> 3;
        const int c16 = t & 7;
        const int swz = (r & 7) << 4;
        const float* xp = x + (size_t)(row0 + r) * D + c16 * 8;
        float4 a0 = *reinterpret_cast<const float4*>(xp);
        float4 a1 = *reinterpret_cast<const float4*>(xp + 4);
        float v[8] = {a0.x, a0.y, a0.z, a0.w, a1.x, a1.y, a1.z, a1.w};
        f16x8 h, l;
#pragma unroll
        for (int j = 0; j < 8; ++j) {
            _Float16 hh = (_Float16)v[j];
            h[j] = hh;
            l[j] = (_Float16)(v[j] - (float)hh);
        }
        const int off = r * 128 + ((c16 * 16) ^ swz);
        *reinterpret_cast<f16x8*>(XH + off) = h;
        *reinterpret_cast<f16x8*>(XL + off) = l;
    }
    __syncthreads();

    const int lane = t & 63;
    const int w    = t >> 6;        // wave 0..7 -> y-col group w*32
    const int l15  = lane & 15;
    const int lg   = lane >> 4;
    const int swzA = (l15 & 7) << 4;

    // ---- MFMA: A = y (LDS), B = x (LDS); 48 MFMAs / wave ------------------
    f32x4 acc[2][4];
#pragma unroll
    for (int mt = 0; mt < 2; ++mt)
#pragma unroll
        for (int nt = 0; nt < 4; ++nt) acc[mt][nt] = (f32x4){0.f, 0.f, 0.f, 0.f};

#pragma unroll
    for (int kh = 0; kh < 2; ++kh) {
        const int dsw = (kh * 64 + lg * 16) ^ swzA;
        f16x8 yh[2], yl[2], bh[4], bl[4];
#pragma unroll
        for (int mt = 0; mt < 2; ++mt) {
            const int aoff = (w * 32 + mt * 16 + l15) * 128 + dsw;
            yh[mt] = *reinterpret_cast<const f16x8*>(YH + aoff);
            yl[mt] = *reinterpret_cast<const f16x8*>(YL + aoff);
        }
#pragma unroll
        for (int nt = 0; nt < 4; ++nt) {
            const int boff = (nt * 16 + l15) * 128 + dsw;
            bh[nt] = *reinterpret_cast<const f16x8*>(XH + boff);
            bl[nt] = *reinterpret_cast<const f16x8*>(XL + boff);
        }
#pragma unroll
        for (int mt = 0; mt < 2; ++mt)
#pragma unroll
            for (int nt = 0; nt < 4; ++nt) {
                acc[mt][nt] = __builtin_amdgcn_mfma_f32_16x16x32_f16(yh[mt], bh[nt], acc[mt][nt], 0, 0, 0);
                acc[mt][nt] = __builtin_amdgcn_mfma_f32_16x16x32_f16(yl[mt], bh[nt], acc[mt][nt], 0, 0, 0);
                acc[mt][nt] = __builtin_amdgcn_mfma_f32_16x16x32_f16(yh[mt], bl[nt], acc[mt][nt], 0, 0, 0);
            }
    }

    // ---- exp in regs (norms from prepass, L2-hit loads) -------------------
    float xsqv[4];
#pragma unroll
    for (int nt = 0; nt < 4; ++nt) xsqv[nt] = sq[row0 + nt * 16 + l15];
#pragma unroll
    for (int mt = 0; mt < 2; ++mt) {
        float4 q = *reinterpret_cast<const float4*>(sq + NROW + col0 + w * 32 + mt * 16 + lg * 4);
        float ys[4] = {q.x, q.y, q.z, q.w};
#pragma unroll
        for (int nt = 0; nt < 4; ++nt)
#pragma unroll
            for (int r = 0; r < 4; ++r) {
                float d2 = fmaxf(fmaf(-2.f, acc[mt][nt][r], xsqv[nt] + ys[r]), 0.f);
                acc[mt][nt][r] = __expf(-d2);
            }
    }
    __syncthreads();   // all waves done reading Y planes before S overlay

    // ---- transpose through S: lane frag (4 y-cols x 1 x-row) -> S --------
    // S[row=x-row][col=y-col]: byte = row*1024 + (chunk*16 ^ (row&7)<<4),
    // chunk = (w*8 + mt*4 + lg). Coverage: row (nt,l15)=64, chunk (w,mt,lg)=64.
#pragma unroll
    for (int mt = 0; mt < 2; ++mt)
#pragma unroll
        for (int nt = 0; nt < 4; ++nt) {
            const int srow = nt * 16 + l15;
            const int off  = srow * 1024 + (((w * 8 + mt * 4 + lg) * 16) ^ ((srow & 7) << 4));
            *reinterpret_cast<f32x4*>(S + off) = acc[mt][nt];
        }
    __syncthreads();   // cross-wave: S rows written by all waves

    // ---- 1-KB-contiguous row stores: wave w sweeps rows w*8..w*8+7 --------
#pragma unroll
    for (int it = 0; it < 8; ++it) {
        const int row = w * 8 + it;
        const int off = row * 1024 + ((lane * 16) ^ ((row & 7) << 4));
        f32x4 v = *reinterpret_cast<const f32x4*>(S + off);
        *reinterpret_cast<f32x4*>(out + (size_t)(row0 + row) * NROW + col0 + lane * 4) = v;
    }
}

extern "C" void kernel_launch(void* const* d_in, const int* in_sizes, int n_in,
                              void* d_out, int out_size, void* d_ws, size_t ws_size,
                              hipStream_t stream) {
    const float* x = (const float*)d_in[0];
    const float* y = (const float*)d_in[1];
    float* out = (float*)d_out;
    float* sq  = (float*)d_ws;   // 16384 floats = 64 KiB (proven R1)

    rbf_rowsq<<<64, 256, 0, stream>>>(x, y, sq);
    rbf_strip<<<4096, 512, 0, stream>>>(x, y, sq, out);
}